// Round 4
// baseline (335.941 us; speedup 1.0000x reference)
//
#include <hip/hip_runtime.h>
#include <hip/hip_bf16.h>

#define B_N 16
#define LP_N 1024
#define LQ_N 1024
#define H_N 1024

typedef unsigned short u16;
typedef __attribute__((ext_vector_type(8))) short bf16x8;
typedef __attribute__((ext_vector_type(4))) float f32x4;

__device__ __forceinline__ u16 f2bf(float x) {
    __hip_bfloat16 h = __float2bfloat16(x);
    return *(u16*)&h;
}
__device__ __forceinline__ float bf2f(u16 u) {
    __hip_bfloat16 h;
    *(u16*)&h = u;
    return __bfloat162float(h);
}

__device__ __forceinline__ void load_lds16(const u16* g, u16* l) {
    __builtin_amdgcn_global_load_lds(
        (const __attribute__((address_space(1))) void*)g,
        (__attribute__((address_space(3))) void*)l, 16, 0, 0);
}

#define MFMA_B16(a, b, c) __builtin_amdgcn_mfma_f32_16x16x32_bf16(a, b, c, 0, 0, 0)
#define VMW(N) asm volatile("s_waitcnt vmcnt(" #N ")" ::: "memory")
#define SBAR() __builtin_amdgcn_s_barrier()

// ---------------------------------------------------------------------------
// 256x256 split-bf16 MFMA GEMM, NT form, 4-phase counted-vmcnt schedule (T3+T4+T5).
// BK=32, 8 waves (2M x 4N), per-wave 128x64. Phase p computes row-frags
// {2p, 2p+1} (rows [32p,32p+32) of each wave-half) and issues the staging
// loads for tile t+1 that phase p of tile t+1 will read (phase-sliced A
// groups; B issued at phase 0). Steady-state wait is vmcnt(8) everywhere
// (FIFO: 8 loads/tile in flight, oldest retire exactly when needed); the
// tail tile drains 3/2/1/0 (split) or 1/0 (dense). Raw s_barrier (no
// vmcnt(0) drain — the point). Swizzle: phys 16B slot = log ^ ((row>>1)&3),
// pre-swizzled global source + swizzled ds_read (R3-verified, 0 conflicts).
// EPI: 0 = fp32 store, 1 = +bias & split bf16 hi/lo store, 2 = relu fp32.
// ---------------------------------------------------------------------------
template<bool SPLIT, int EPI>
__launch_bounds__(512, 2)
__global__ void gemm8p(const u16* __restrict__ Ahi, const u16* __restrict__ Alo,
                       const u16* __restrict__ Bhi, const u16* __restrict__ Blo,
                       const float* __restrict__ bias,
                       float* __restrict__ Cf, u16* __restrict__ Chi, u16* __restrict__ Clo,
                       int N, int K, int gn, int gmn,
                       long long sA, long long sB, long long sC)
{
    constexpr int SUB = 8192;                    // u16 per 256x32 sub-tile (16 KB)
    constexpr int NSUB = SPLIT ? 4 : 2;          // [Ahi][Alo][Bhi][Blo] | [Ahi][Bhi]
    constexpr int BHI = SPLIT ? 2 * SUB : SUB;
    constexpr int BLO = SPLIT ? 3 * SUB : 0;
    __shared__ __align__(16) u16 buf0[NSUB * SUB];
    __shared__ __align__(16) u16 buf1[NSUB * SUB];

    const int tid  = threadIdx.x;
    const int lane = tid & 63;
    const int wv   = tid >> 6;
    const int wr   = wv >> 2, wc = wv & 3;       // 2M x 4N waves

    // XCD-contiguous block swizzle (nwg=256 -> 32 contiguous tiles/XCD)
    const int d   = blockIdx.x;
    const int cpx = gridDim.x >> 3;
    const int swz = (d & 7) * cpx + (d >> 3);
    const long long z = swz / gmn;
    const int r_  = swz % gmn;
    const int bm  = (r_ / gn) * 256;
    const int bn  = (r_ % gn) * 256;

    // ---- B staging: 1024 chunks (rows 0..255 x 4 slots), 2 per thread.
    const int bc0 = tid, bc1 = tid + 512;
    const int br0 = bc0 >> 2, bs0 = (bc0 & 3) ^ ((br0 >> 1) & 3);
    const int br1 = bc1 >> 2, bs1 = (bc1 & 3) ^ ((br1 >> 1) & 3);
    const u16* pBh0 = Bhi + z * sB + (long long)(bn + br0) * K + bs0 * 8;
    const u16* pBh1 = Bhi + z * sB + (long long)(bn + br1) * K + bs1 * 8;
    const u16* pBl0 = SPLIT ? (Blo + z * sB + (long long)(bn + br0) * K + bs0 * 8) : pBh0;
    const u16* pBl1 = SPLIT ? (Blo + z * sB + (long long)(bn + br1) * K + bs1 * 8) : pBh1;
    const int dB0 = bc0 * 8, dB1 = bc1 * 8;      // u16 offsets within B sub-tile

    // ---- A staging, phase-sliced groups. Group g holds exactly the rows
    // phase g reads: split -> rows [32g,32g+32) U [128+32g,+32) x (hi,lo),
    // 1 chunk/thread; dense -> rows [64g,64g+64) U [128+64g,+64), groups 0,1.
    int arp, asl, ahalf;
    if constexpr (SPLIT) {
        ahalf = tid >> 8;                        // 0=hi, 1=lo (waves 0-3 / 4-7)
        const int idx = tid & 255;
        const int rl  = idx >> 2;
        asl = idx & 3;
        arp = (rl & 31) + (rl >> 5) * 128;       // base row within group
    } else {
        ahalf = 0;
        const int rl = tid >> 2;
        asl = tid & 3;
        arp = (rl & 63) + (rl >> 6) * 128;
    }
    const int aswz = asl ^ ((arp >> 1) & 3);     // group offset (32g/64g) is 0 mod 4
    constexpr int GSTEP = SPLIT ? 32 : 64;
    const u16* Asrc = (SPLIT && ahalf) ? Alo : Ahi;
    const u16* pA0 = Asrc + z * sA + (long long)(bm + arp + 0 * GSTEP) * K + aswz * 8;
    const u16* pA1 = Asrc + z * sA + (long long)(bm + arp + 1 * GSTEP) * K + aswz * 8;
    const u16* pA2 = SPLIT ? (Asrc + z * sA + (long long)(bm + arp + 2 * GSTEP) * K + aswz * 8) : pA0;
    const u16* pA3 = SPLIT ? (Asrc + z * sA + (long long)(bm + arp + 3 * GSTEP) * K + aswz * 8) : pA1;
    const int ahbase = (SPLIT && ahalf) ? SUB : 0;
    const int dA0 = ahbase + (arp + 0 * GSTEP) * 32 + asl * 8;
    const int dA1 = ahbase + (arp + 1 * GSTEP) * 32 + asl * 8;
    const int dA2 = SPLIT ? (ahbase + (arp + 2 * GSTEP) * 32 + asl * 8) : dA0;
    const int dA3 = SPLIT ? (ahbase + (arp + 3 * GSTEP) * 32 + asl * 8) : dA1;

    // ---- fragment read offsets (u16 units within sub-tile), swizzled
    int offA[8], offB[4];
#pragma unroll
    for (int i = 0; i < 8; ++i) {
        const int ra = wr * 128 + i * 16 + (lane & 15);
        offA[i] = ra * 32 + (((lane >> 4) ^ ((ra >> 1) & 3)) << 3);
    }
#pragma unroll
    for (int j = 0; j < 4; ++j) {
        const int rb = wc * 64 + j * 16 + (lane & 15);
        offB[j] = rb * 32 + (((lane >> 4) ^ ((rb >> 1) & 3)) << 3);
    }

    f32x4 acc[8][4];
#pragma unroll
    for (int i = 0; i < 8; ++i)
#pragma unroll
        for (int j = 0; j < 4; ++j)
            acc[i][j] = (f32x4){0.f, 0.f, 0.f, 0.f};

#define ISSUE_B(NXT) do {                                                     \
        load_lds16(pBh0, (NXT) + BHI + dB0); load_lds16(pBh1, (NXT) + BHI + dB1); \
        if constexpr (SPLIT) {                                                \
            load_lds16(pBl0, (NXT) + BLO + dB0); load_lds16(pBl1, (NXT) + BLO + dB1); \
            pBl0 += 32; pBl1 += 32;                                           \
        }                                                                     \
        pBh0 += 32; pBh1 += 32;                                               \
    } while (0)

#define ISSUE_A(NXT, G) do { load_lds16(pA##G, (NXT) + dA##G); pA##G += 32; } while (0)

#define READ_B(CUR) do {                                                      \
        _Pragma("unroll")                                                     \
        for (int j = 0; j < 4; ++j) {                                         \
            bh[j] = *(const bf16x8*)((CUR) + BHI + offB[j]);                  \
            if constexpr (SPLIT) bl[j] = *(const bf16x8*)((CUR) + BLO + offB[j]); \
        }                                                                     \
    } while (0)

#define PHASE_MFMA(CUR, P) do {                                               \
        const bf16x8 ah0 = *(const bf16x8*)((CUR) + offA[2 * (P)]);           \
        const bf16x8 ah1 = *(const bf16x8*)((CUR) + offA[2 * (P) + 1]);       \
        bf16x8 al0{}, al1{};                                                  \
        if constexpr (SPLIT) {                                                \
            al0 = *(const bf16x8*)((CUR) + SUB + offA[2 * (P)]);              \
            al1 = *(const bf16x8*)((CUR) + SUB + offA[2 * (P) + 1]);          \
        }                                                                     \
        __builtin_amdgcn_s_setprio(1);                                        \
        _Pragma("unroll")                                                     \
        for (int j = 0; j < 4; ++j) {                                         \
            acc[2 * (P)][j]     = MFMA_B16(ah0, bh[j], acc[2 * (P)][j]);      \
            acc[2 * (P) + 1][j] = MFMA_B16(ah1, bh[j], acc[2 * (P) + 1][j]);  \
            if constexpr (SPLIT) {                                            \
                acc[2 * (P)][j]     = MFMA_B16(ah0, bl[j], acc[2 * (P)][j]);  \
                acc[2 * (P)][j]     = MFMA_B16(al0, bh[j], acc[2 * (P)][j]);  \
                acc[2 * (P) + 1][j] = MFMA_B16(ah1, bl[j], acc[2 * (P) + 1][j]); \
                acc[2 * (P) + 1][j] = MFMA_B16(al1, bh[j], acc[2 * (P) + 1][j]); \
            }                                                                 \
        }                                                                     \
        __builtin_amdgcn_s_setprio(0);                                        \
    } while (0)

    const int NT = K >> 5;

    // prologue: issue all of tile 0 (canonical order: B, Ag0..Ag3)
    ISSUE_B(buf0);
    ISSUE_A(buf0, 0);
    ISSUE_A(buf0, 1);
    if constexpr (SPLIT) { ISSUE_A(buf0, 2); ISSUE_A(buf0, 3); }

    for (int t = 0; t < NT - 1; ++t) {
        u16* cur = (t & 1) ? buf1 : buf0;
        u16* nxt = (t & 1) ? buf0 : buf1;
        bf16x8 bh[4], bl[4];
        // phase 0
        ISSUE_B(nxt); ISSUE_A(nxt, 0);
        if constexpr (SPLIT) VMW(8); else VMW(4);
        SBAR();
        READ_B(cur);
        PHASE_MFMA(cur, 0);
        SBAR();
        // phase 1
        ISSUE_A(nxt, 1);
        if constexpr (SPLIT) VMW(8); else VMW(4);
        SBAR();
        PHASE_MFMA(cur, 1);
        SBAR();
        // phase 2
        if constexpr (SPLIT) { ISSUE_A(nxt, 2); VMW(8); }
        SBAR();
        PHASE_MFMA(cur, 2);
        SBAR();
        // phase 3
        if constexpr (SPLIT) { ISSUE_A(nxt, 3); VMW(8); }
        SBAR();
        PHASE_MFMA(cur, 3);
        SBAR();
    }
    // tail tile NT-1: no issues; drain counted
    {
        u16* cur = ((NT - 1) & 1) ? buf1 : buf0;
        bf16x8 bh[4], bl[4];
        if constexpr (SPLIT) VMW(3); else VMW(1);
        SBAR();
        READ_B(cur);
        PHASE_MFMA(cur, 0);
        SBAR();
        if constexpr (SPLIT) VMW(2); else VMW(0);
        SBAR();
        PHASE_MFMA(cur, 1);
        SBAR();
        if constexpr (SPLIT) VMW(1);
        SBAR();
        PHASE_MFMA(cur, 2);
        SBAR();
        if constexpr (SPLIT) VMW(0);
        SBAR();
        PHASE_MFMA(cur, 3);
    }
#undef ISSUE_B
#undef ISSUE_A
#undef READ_B
#undef PHASE_MFMA

    // epilogue; C/D map: col = lane&15, row = (lane>>4)*4 + e  [m89/m91]
    const long long Cbase = z * sC;
#pragma unroll
    for (int i = 0; i < 8; ++i) {
        const int row0 = bm + wr * 128 + i * 16 + ((lane >> 4) << 2);
#pragma unroll
        for (int j = 0; j < 4; ++j) {
            const int col = bn + wc * 64 + j * 16 + (lane & 15);
#pragma unroll
            for (int e = 0; e < 4; ++e) {
                const float v = acc[i][j][e];
                const long long idx = Cbase + (long long)(row0 + e) * N + col;
                if constexpr (EPI == 0) {
                    Cf[idx] = v;
                } else if constexpr (EPI == 1) {
                    const float vb = v + bias[col];
                    const u16 h = f2bf(vb);
                    Chi[idx] = h;
                    Clo[idx] = f2bf(vb - bf2f(h));
                } else {
                    Cf[idx] = fmaxf(v, 0.f);
                }
            }
        }
    }
}

// fp32 -> bf16 hi/lo split, 4 elems/thread
__global__ void split_cvt(const float* __restrict__ in, u16* __restrict__ hi,
                          u16* __restrict__ lo, long long n4)
{
    const long long i = (long long)blockIdx.x * 256 + threadIdx.x;
    if (i >= n4) return;
    const float4 v = ((const float4*)in)[i];
    ushort4 h, l;
    h.x = f2bf(v.x); l.x = f2bf(v.x - bf2f(h.x));
    h.y = f2bf(v.y); l.y = f2bf(v.y - bf2f(h.y));
    h.z = f2bf(v.z); l.z = f2bf(v.z - bf2f(h.z));
    h.w = f2bf(v.w); l.w = f2bf(v.w - bf2f(h.w));
    ((ushort4*)hi)[i] = h;
    ((ushort4*)lo)[i] = l;
}

// out[c][r] = in[r][c] with bf16 (hi[,lo]) conversion; in: R x C per batch z
template<bool LO>
__global__ void transpose_cvt(const float* __restrict__ in, u16* __restrict__ hi,
                              u16* __restrict__ lo, int R, int C,
                              long long sIn, long long sOut)
{
    __shared__ float t[32][33];
    const long long z = blockIdx.z;
    const float* I = in + z * sIn;
    const int r0 = blockIdx.y * 32, c0 = blockIdx.x * 32;
    for (int j = threadIdx.y; j < 32; j += 8)
        t[j][threadIdx.x] = I[(long long)(r0 + j) * C + c0 + threadIdx.x];
    __syncthreads();
    for (int j = threadIdx.y; j < 32; j += 8) {
        const float v = t[threadIdx.x][j];
        const long long o = z * sOut + (long long)(c0 + j) * R + r0 + threadIdx.x;
        const u16 h = f2bf(v);
        hi[o] = h;
        if (LO) lo[o] = f2bf(v - bf2f(h));
    }
}

// row softmax (fp32 in, bf16 out), one 256-thread block per 1024-elem row
__global__ void softmax_bf16(const float* __restrict__ S, u16* __restrict__ A)
{
    const long long row = blockIdx.x;
    const float* r = S + row * (long long)LQ_N;
    const int t = threadIdx.x;
    float4 v = ((const float4*)r)[t];

    float m = fmaxf(fmaxf(v.x, v.y), fmaxf(v.z, v.w));
#pragma unroll
    for (int off = 32; off > 0; off >>= 1)
        m = fmaxf(m, __shfl_xor(m, off));

    __shared__ float red[4];
    const int lane = t & 63, wid = t >> 6;
    if (lane == 0) red[wid] = m;
    __syncthreads();
    m = fmaxf(fmaxf(red[0], red[1]), fmaxf(red[2], red[3]));
    __syncthreads();

    v.x = __expf(v.x - m); v.y = __expf(v.y - m);
    v.z = __expf(v.z - m); v.w = __expf(v.w - m);
    float s = v.x + v.y + v.z + v.w;
#pragma unroll
    for (int off = 32; off > 0; off >>= 1)
        s += __shfl_xor(s, off);
    if (lane == 0) red[wid] = s;
    __syncthreads();
    s = red[0] + red[1] + red[2] + red[3];

    const float inv = 1.0f / s;
    ushort4 o;
    o.x = f2bf(v.x * inv); o.y = f2bf(v.y * inv);
    o.z = f2bf(v.z * inv); o.w = f2bf(v.w * inv);
    ((ushort4*)(A + row * (long long)LQ_N))[t] = o;
}

// ---------------------------------------------------------------------------
// Fallback fp32 path (round-1, verified; needs only 128 MB ws)
// ---------------------------------------------------------------------------
#define BM 128
#define BN 128
#define BK 8
#define TM 8
#define TN 8

template<bool TRANSB, bool BIAS, bool RELU>
__launch_bounds__(256)
__global__ void gemm_k(const float* __restrict__ A, const float* __restrict__ Bmat,
                       const float* __restrict__ bias, float* __restrict__ C,
                       int M, int N, int K,
                       long long sA, long long sB, long long sC)
{
    __shared__ float As[BK][BM];
    __shared__ float Bs[BK][BN];
    const int tid = threadIdx.x;
    const int tx = tid & 15;
    const int ty = tid >> 4;
    const int bn = blockIdx.x * BN;
    const int bm = blockIdx.y * BM;
    const long long z = blockIdx.z;
    A += z * sA; Bmat += z * sB; C += z * sC;
    float acc[TM][TN];
#pragma unroll
    for (int i = 0; i < TM; i++)
#pragma unroll
        for (int j = 0; j < TN; j++) acc[i][j] = 0.f;
    const int arow = tid >> 1;
    const int acol = (tid & 1) * 4;
    const int bk_n = tid >> 5;
    const int bn_n = (tid & 31) * 4;
    for (int k0 = 0; k0 < K; k0 += BK) {
        float4 a4 = *(const float4*)&A[(long long)(bm + arow) * K + k0 + acol];
        As[acol + 0][arow] = a4.x; As[acol + 1][arow] = a4.y;
        As[acol + 2][arow] = a4.z; As[acol + 3][arow] = a4.w;
        if (TRANSB) {
            float4 b4 = *(const float4*)&Bmat[(long long)(bn + arow) * K + k0 + acol];
            Bs[acol + 0][arow] = b4.x; Bs[acol + 1][arow] = b4.y;
            Bs[acol + 2][arow] = b4.z; Bs[acol + 3][arow] = b4.w;
        } else {
            float4 b4 = *(const float4*)&Bmat[(long long)(k0 + bk_n) * N + bn + bn_n];
            *(float4*)&Bs[bk_n][bn_n] = b4;
        }
        __syncthreads();
#pragma unroll
        for (int k = 0; k < BK; k++) {
            float a[TM], b[TN];
            *(float4*)&a[0] = *(const float4*)&As[k][ty * TM];
            *(float4*)&a[4] = *(const float4*)&As[k][ty * TM + 4];
            *(float4*)&b[0] = *(const float4*)&Bs[k][tx * TN];
            *(float4*)&b[4] = *(const float4*)&Bs[k][tx * TN + 4];
#pragma unroll
            for (int i = 0; i < TM; i++)
#pragma unroll
                for (int j = 0; j < TN; j++)
                    acc[i][j] = fmaf(a[i], b[j], acc[i][j]);
        }
        __syncthreads();
    }
#pragma unroll
    for (int i = 0; i < TM; i++) {
        const int row = bm + ty * TM + i;
#pragma unroll
        for (int j = 0; j < TN; j += 4) {
            const int col = bn + tx * TN + j;
            float4 v;
            v.x = acc[i][j + 0]; v.y = acc[i][j + 1];
            v.z = acc[i][j + 2]; v.w = acc[i][j + 3];
            if (BIAS) {
                v.x += bias[col + 0]; v.y += bias[col + 1];
                v.z += bias[col + 2]; v.w += bias[col + 3];
            }
            if (RELU) {
                v.x = fmaxf(v.x, 0.f); v.y = fmaxf(v.y, 0.f);
                v.z = fmaxf(v.z, 0.f); v.w = fmaxf(v.w, 0.f);
            }
            *(float4*)&C[(long long)row * N + col] = v;
        }
    }
}

__global__ void softmax_k(float* __restrict__ S)
{
    const long long row = blockIdx.x;
    float* r = S + row * (long long)LQ_N;
    const int t = threadIdx.x;
    float4 v = ((float4*)r)[t];
    float m = fmaxf(fmaxf(v.x, v.y), fmaxf(v.z, v.w));
#pragma unroll
    for (int off = 32; off > 0; off >>= 1)
        m = fmaxf(m, __shfl_xor(m, off));
    __shared__ float red[4];
    const int lane = t & 63, wid = t >> 6;
    if (lane == 0) red[wid] = m;
    __syncthreads();
    m = fmaxf(fmaxf(red[0], red[1]), fmaxf(red[2], red[3]));
    __syncthreads();
    v.x = __expf(v.x - m); v.y = __expf(v.y - m);
    v.z = __expf(v.z - m); v.w = __expf(v.w - m);
    float s = v.x + v.y + v.z + v.w;
#pragma unroll
    for (int off = 32; off > 0; off >>= 1)
        s += __shfl_xor(s, off);
    if (lane == 0) red[wid] = s;
    __syncthreads();
    s = red[0] + red[1] + red[2] + red[3];
    const float inv = 1.0f / s;
    v.x *= inv; v.y *= inv; v.z *= inv; v.w *= inv;
    ((float4*)r)[t] = v;
}

extern "C" void kernel_launch(void* const* d_in, const int* in_sizes, int n_in,
                              void* d_out, int out_size, void* d_ws, size_t ws_size,
                              hipStream_t stream)
{
    const float* p    = (const float*)d_in[0];
    const float* q    = (const float*)d_in[1];
    const float* W    = (const float*)d_in[2];
    const float* bias = (const float*)d_in[3];
    float* out = (float*)d_out;

    const size_t MB32 = 33554432ull;                 // 16M bf16
    const size_t NEED = 7 * MB32 + 2 * 2097152ull;   // 228 MB + 4 MB

    if (ws_size >= NEED) {
        char* w = (char*)d_ws;
        u16* p_hi    = (u16*)(w + 0 * MB32);
        u16* p_lo    = (u16*)(w + 1 * MB32);
        u16* q_hi    = (u16*)(w + 2 * MB32);
        u16* q_lo    = (u16*)(w + 3 * MB32);
        u16* keys_hi = (u16*)(w + 4 * MB32);
        u16* keys_lo = (u16*)(w + 5 * MB32);
        u16* qT_hi   = (u16*)(w + 6 * MB32);
        u16* Wt_hi   = (u16*)(w + 7 * MB32);
        u16* Wt_lo   = (u16*)(w + 7 * MB32 + 2097152);
        float* scores = (float*)(w + 2 * MB32);  // reuses q_hi/q_lo after GEMM1
        u16* attn     = (u16*)(w + 0 * MB32);    // reuses p_hi after GEMM2

        const long long n4 = (long long)B_N * LQ_N * H_N / 4;
        split_cvt<<<dim3((unsigned)(n4 / 256)), 256, 0, stream>>>(p, p_hi, p_lo, n4);
        split_cvt<<<dim3((unsigned)(n4 / 256)), 256, 0, stream>>>(q, q_hi, q_lo, n4);
        transpose_cvt<true><<<dim3(32, 32, 1), dim3(32, 8), 0, stream>>>(
            W, Wt_hi, Wt_lo, H_N, H_N, 0, 0);
        transpose_cvt<false><<<dim3(32, 32, B_N), dim3(32, 8), 0, stream>>>(
            q, qT_hi, nullptr, LQ_N, H_N,
            (long long)LQ_N * H_N, (long long)LQ_N * H_N);

        // keys = q @ W + b : M=16384 (batch folded), N=1024. grid 64x4 = 256.
        gemm8p<true, 1><<<256, 512, 0, stream>>>(
            q_hi, q_lo, Wt_hi, Wt_lo, bias, nullptr, keys_hi, keys_lo,
            H_N, H_N, /*gn=*/4, /*gmn=*/256, 0, 0, 0);

        // scores[b] = p[b] @ keys[b]^T : per batch 4x4 tiles, 16 batches.
        gemm8p<true, 0><<<256, 512, 0, stream>>>(
            p_hi, p_lo, keys_hi, keys_lo, nullptr, scores, nullptr, nullptr,
            LQ_N, H_N, /*gn=*/4, /*gmn=*/16,
            (long long)LP_N * H_N, (long long)LQ_N * H_N, (long long)LP_N * LQ_N);

        softmax_bf16<<<B_N * LP_N, 256, 0, stream>>>(scores, attn);

        // out[b] = relu(attn[b] @ q[b]) : dense bf16.
        gemm8p<false, 2><<<256, 512, 0, stream>>>(
            attn, nullptr, qT_hi, nullptr, nullptr, out, nullptr, nullptr,
            H_N, LQ_N, /*gn=*/4, /*gmn=*/16,
            (long long)LP_N * LQ_N, (long long)H_N * LQ_N, (long long)LP_N * H_N);
    } else {
        float* keys   = (float*)d_ws;
        float* scores = keys + (long long)B_N * LQ_N * H_N;

        gemm_k<false, true, false><<<dim3(H_N / BN, (B_N * LQ_N) / BM, 1), 256, 0, stream>>>(
            q, W, bias, keys, B_N * LQ_N, H_N, H_N, 0, 0, 0);
        gemm_k<true, false, false><<<dim3(LQ_N / BN, LP_N / BM, B_N), 256, 0, stream>>>(
            p, keys, nullptr, scores, LP_N, LQ_N, H_N,
            (long long)LP_N * H_N, (long long)LQ_N * H_N, (long long)LP_N * LQ_N);
        softmax_k<<<B_N * LP_N, 256, 0, stream>>>(scores);
        gemm_k<false, false, true><<<dim3(H_N / BN, LP_N / BM, B_N), 256, 0, stream>>>(
            scores, q, nullptr, out, LP_N, H_N, LQ_N,
            (long long)LP_N * LQ_N, (long long)LQ_N * H_N, (long long)LP_N * H_N);
    }
}

// Round 6
// 298.813 us; speedup vs baseline: 1.1243x; 1.1243x over previous
//
#include <hip/hip_runtime.h>
#include <hip/hip_bf16.h>

#define B_N 16
#define LP_N 1024
#define LQ_N 1024
#define H_N 1024

typedef unsigned short u16;
typedef __attribute__((ext_vector_type(8))) short bf16x8;
typedef __attribute__((ext_vector_type(4))) float f32x4;

__device__ __forceinline__ u16 f2bf(float x) {
    __hip_bfloat16 h = __float2bfloat16(x);
    return *(u16*)&h;
}
__device__ __forceinline__ float bf2f(u16 u) {
    __hip_bfloat16 h;
    *(u16*)&h = u;
    return __bfloat162float(h);
}

__device__ __forceinline__ void load_lds16(const u16* g, u16* l) {
    __builtin_amdgcn_global_load_lds(
        (const __attribute__((address_space(1))) void*)g,
        (__attribute__((address_space(3))) void*)l, 16, 0, 0);
}

#define MFMA_B16(a, b, c) __builtin_amdgcn_mfma_f32_16x16x32_bf16(a, b, c, 0, 0, 0)
#define VMW0()  asm volatile("s_waitcnt vmcnt(0)" ::: "memory")
#define LGKM4() asm volatile("s_waitcnt lgkmcnt(4)" ::: "memory")
#define LGKM0() asm volatile("s_waitcnt lgkmcnt(0)" ::: "memory")
#define SCHB()  __builtin_amdgcn_sched_barrier(0)
#define SBAR()  __builtin_amdgcn_s_barrier()

// ---------------------------------------------------------------------------
// 256x256 dense-bf16 MFMA GEMM, NT form, register-pipelined schedule.
// K is virtualized over SEGS segments of 1024 (K-concat): split-bf16 GEMM
// (hi*hi + hi*lo + lo*hi) = dense GEMM over [Ahi|Ahi|Alo] x [Bhi|Blo|Bhi].
// BK=64, 8 waves (2M x 4N), per-wave 128x64 = 8x4 frags, 2 subk/tile.
// Per K-tile: 1 vmcnt(0) gate + 1 s_barrier, then 4 phases. All 8 staging
// loads for tile t+1 are issued in phases 0-1 (B then A) so the youngest
// load has >=2.5 phases of compute before the next gate (covers HBM miss);
// phase p also ds_reads A-frags for phase p+1 and waits lgkmcnt(4):
//   FIFO after gate: bb(8)+ga0(4); +4/phase -> waits 4/4/4/0.
// R5 BUG FIX: stage destinations now carry the +H*8192 half offset (rows
// [128,256) of each 256x64 tile region); R5 wrote both halves to the same
// place -> half of every tile was stale LDS -> absmax inf.
// B-frags (8 b128) are read once per tile and live in regs all 4 phases.
// Swizzle: 16B slot s_phys = s_log ^ (row&7); linear LDS dest (m104 rule),
// pre-swizzled global source, swizzled ds_read (both-sides, rule #21).
// EPI: 0 = fp32 store, 1 = +bias & split bf16 hi/lo store, 2 = relu fp32.
// ---------------------------------------------------------------------------
template<int SEGS, int EPI>
__launch_bounds__(512, 2)
__global__ void gemm_pipe(const u16* __restrict__ pa0, const u16* __restrict__ pa1,
                          const u16* __restrict__ pa2,
                          const u16* __restrict__ pb0, const u16* __restrict__ pb1,
                          const u16* __restrict__ pb2,
                          const float* __restrict__ bias,
                          float* __restrict__ Cf, u16* __restrict__ Chi, u16* __restrict__ Clo,
                          int N, int gn, int gmn,
                          long long sA, long long sB, long long sC)
{
    __shared__ __align__(16) u16 lds[65536];     // 2 x (A 32KB + B 32KB)

    const int tid  = threadIdx.x;
    const int lane = tid & 63;
    const int wv   = tid >> 6;
    const int wr   = wv >> 2, wc = wv & 3;       // 2M x 4N waves

    // XCD-contiguous block swizzle (nwg=256 -> 32 contiguous tiles/XCD)
    const int d   = blockIdx.x;
    const int cpx = gridDim.x >> 3;
    const int swz = (d & 7) * cpx + (d >> 3);
    const long long z = swz / gmn;
    const int r_  = swz % gmn;
    const int bm  = (r_ / gn) * 256;
    const int bn  = (r_ % gn) * 256;

    const char* A0 = (const char*)(pa0 + z * sA);
    const char* A1 = (const char*)(pa1 + z * sA);
    const char* A2 = (const char*)(pa2 + z * sA);
    const char* B0 = (const char*)(pb0 + z * sB);
    const char* B1 = (const char*)(pb1 + z * sB);
    const char* B2 = (const char*)(pb2 + z * sB);

    // ---- staging geometry: half-tile = 128 rows x 64 cols = 1024 x 16B
    // chunk c: row = c>>3, phys slot = c&7; source logical slot = (c&7)^(row&7).
    // thread handles chunks {tid, tid+512} (rows r0, r0+64; same XOR since
    // (r0+64)&7 == r0&7). Row stride in every source matrix = 1024 elem = 2048 B.
    const int r0 = tid >> 3;                     // 0..63
    const int xc = (tid & 7) ^ (r0 & 7);
    const long long aoff = (long long)(bm + r0) * 2048 + xc * 16;
    const long long boff = (long long)(bn + r0) * 2048 + xc * 16;
    const int dA = tid * 8;                      // u16 dest offset, A region
    const int dB = 16384 + tid * 8;              // B region

    // ---- fragment ds_read offsets (u16 units), same swizzle
    const int sl0 = (((lane >> 4) + 0) ^ (lane & 7)) * 8;   // subk 0 slot
    const int sl1 = (((lane >> 4) + 4) ^ (lane & 7)) * 8;   // subk 1 slot
    const int rbA = (wr * 128 + (lane & 15)) * 64;
    const int rbB = 16384 + (wc * 64 + (lane & 15)) * 64;

    f32x4 acc[8][4];
#pragma unroll
    for (int i = 0; i < 8; ++i)
#pragma unroll
        for (int j = 0; j < 4; ++j)
            acc[i][j] = (f32x4){0.f, 0.f, 0.f, 0.f};

    bf16x8 bb[4][2];        // B frags: 4 cols x 2 subk, live whole tile
    bf16x8 ga0[2][2];       // A frags ping (row pair, 2 subk)
    bf16x8 ga1[2][2];       // A frags pong

#define STG_B(H, NB) do {                                                     \
        load_lds16((const u16*)(bseg + boff + kb + (H) * 262144),             \
                   lds + (NB) + (H) * 8192 + dB);                             \
        load_lds16((const u16*)(bseg + boff + kb + (H) * 262144 + 131072),    \
                   lds + (NB) + (H) * 8192 + dB + 4096);                      \
    } while (0)
#define STG_A(H, NB) do {                                                     \
        load_lds16((const u16*)(aseg + aoff + kb + (H) * 262144),             \
                   lds + (NB) + (H) * 8192 + dA);                             \
        load_lds16((const u16*)(aseg + aoff + kb + (H) * 262144 + 131072),    \
                   lds + (NB) + (H) * 8192 + dA + 4096);                      \
    } while (0)
#define RD_A(G, I0, CB) do {                                                  \
        G[0][0] = *(const bf16x8*)(lds + (CB) + rbA + (I0) * 1024 + sl0);     \
        G[0][1] = *(const bf16x8*)(lds + (CB) + rbA + (I0) * 1024 + sl1);     \
        G[1][0] = *(const bf16x8*)(lds + (CB) + rbA + ((I0) + 1) * 1024 + sl0); \
        G[1][1] = *(const bf16x8*)(lds + (CB) + rbA + ((I0) + 1) * 1024 + sl1); \
    } while (0)
#define RD_B(CB) do {                                                         \
        _Pragma("unroll")                                                     \
        for (int j = 0; j < 4; ++j) {                                         \
            bb[j][0] = *(const bf16x8*)(lds + (CB) + rbB + j * 1024 + sl0);   \
            bb[j][1] = *(const bf16x8*)(lds + (CB) + rbB + j * 1024 + sl1);   \
        }                                                                     \
    } while (0)
#define PH_MFMA(G, I0) do {                                                   \
        __builtin_amdgcn_s_setprio(1);                                        \
        _Pragma("unroll")                                                     \
        for (int j = 0; j < 4; ++j) {                                         \
            acc[(I0)][j]     = MFMA_B16(G[0][0], bb[j][0], acc[(I0)][j]);     \
            acc[(I0)][j]     = MFMA_B16(G[0][1], bb[j][1], acc[(I0)][j]);     \
            acc[(I0) + 1][j] = MFMA_B16(G[1][0], bb[j][0], acc[(I0) + 1][j]); \
            acc[(I0) + 1][j] = MFMA_B16(G[1][1], bb[j][1], acc[(I0) + 1][j]); \
        }                                                                     \
        __builtin_amdgcn_s_setprio(0);                                        \
    } while (0)

    const int NT = SEGS * 16;                    // K-tiles of 64

    // prologue: stage tile 0 (seg 0, kin 0) into buffer 0
    {
        const char* aseg = A0;
        const char* bseg = B0;
        const long long kb = 0;
        STG_B(0, 0); STG_B(1, 0); STG_A(0, 0); STG_A(1, 0);
    }

    for (int t = 0; t < NT; ++t) {
        const int cb = (t & 1) << 15;
        const int nb = ((t + 1) & 1) << 15;
        const bool st = (t + 1) < NT;
        const int s_ = (t + 1) >> 4;
        const long long kb = (long long)(((t + 1) & 15) * 128);
        const char* aseg = (SEGS == 1) ? A0 : (s_ == 0 ? A0 : (s_ == 1 ? A1 : A2));
        const char* bseg = (SEGS == 1) ? B0 : (s_ == 0 ? B0 : (s_ == 1 ? B1 : B2));

        VMW0();                  // tile t's 8 staged loads retired (per wave)
        SBAR();                  // all waves' -> tile t fully in LDS
        RD_B(cb);                // 8 b128
        RD_A(ga0, 0, cb);        // 4 b128 (rows 0,1)
        // phase 0: stage whole B half-pair of t+1 early (max gate slack)
        if (st) { STG_B(0, nb); STG_B(1, nb); }
        RD_A(ga1, 2, cb);
        LGKM4(); SCHB();
        PH_MFMA(ga0, 0);
        // phase 1: stage A of t+1
        if (st) { STG_A(0, nb); STG_A(1, nb); }
        RD_A(ga0, 4, cb);
        LGKM4(); SCHB();
        PH_MFMA(ga1, 2);
        // phase 2
        RD_A(ga1, 6, cb);
        LGKM4(); SCHB();
        PH_MFMA(ga0, 4);
        // phase 3
        LGKM0(); SCHB();
        PH_MFMA(ga1, 6);
    }
#undef STG_B
#undef STG_A
#undef RD_A
#undef RD_B
#undef PH_MFMA

    // epilogue; C/D map: col = lane&15, row = (lane>>4)*4 + e  [m89/m91]
    const long long Cbase = z * sC;
#pragma unroll
    for (int i = 0; i < 8; ++i) {
        const int row0 = bm + wr * 128 + i * 16 + ((lane >> 4) << 2);
#pragma unroll
        for (int j = 0; j < 4; ++j) {
            const int col = bn + wc * 64 + j * 16 + (lane & 15);
#pragma unroll
            for (int e = 0; e < 4; ++e) {
                const float v = acc[i][j][e];
                const long long idx = Cbase + (long long)(row0 + e) * N + col;
                if constexpr (EPI == 0) {
                    Cf[idx] = v;
                } else if constexpr (EPI == 1) {
                    const float vb = v + bias[col];
                    const u16 h = f2bf(vb);
                    Chi[idx] = h;
                    Clo[idx] = f2bf(vb - bf2f(h));
                } else {
                    Cf[idx] = fmaxf(v, 0.f);
                }
            }
        }
    }
}

// fp32 -> bf16 hi/lo split, 4 elems/thread
__global__ void split_cvt(const float* __restrict__ in, u16* __restrict__ hi,
                          u16* __restrict__ lo, long long n4)
{
    const long long i = (long long)blockIdx.x * 256 + threadIdx.x;
    if (i >= n4) return;
    const float4 v = ((const float4*)in)[i];
    ushort4 h, l;
    h.x = f2bf(v.x); l.x = f2bf(v.x - bf2f(h.x));
    h.y = f2bf(v.y); l.y = f2bf(v.y - bf2f(h.y));
    h.z = f2bf(v.z); l.z = f2bf(v.z - bf2f(h.z));
    h.w = f2bf(v.w); l.w = f2bf(v.w - bf2f(h.w));
    ((ushort4*)hi)[i] = h;
    ((ushort4*)lo)[i] = l;
}

// out[c][r] = in[r][c] with bf16 (hi[,lo]) conversion; in: R x C per batch z
template<bool LO>
__global__ void transpose_cvt(const float* __restrict__ in, u16* __restrict__ hi,
                              u16* __restrict__ lo, int R, int C,
                              long long sIn, long long sOut)
{
    __shared__ float t[32][33];
    const long long z = blockIdx.z;
    const float* I = in + z * sIn;
    const int r0 = blockIdx.y * 32, c0 = blockIdx.x * 32;
    for (int j = threadIdx.y; j < 32; j += 8)
        t[j][threadIdx.x] = I[(long long)(r0 + j) * C + c0 + threadIdx.x];
    __syncthreads();
    for (int j = threadIdx.y; j < 32; j += 8) {
        const float v = t[threadIdx.x][j];
        const long long o = z * sOut + (long long)(c0 + j) * R + r0 + threadIdx.x;
        const u16 h = f2bf(v);
        hi[o] = h;
        if (LO) lo[o] = f2bf(v - bf2f(h));
    }
}

// row softmax (fp32 in, bf16 out), one 256-thread block per 1024-elem row
__global__ void softmax_bf16(const float* __restrict__ S, u16* __restrict__ A)
{
    const long long row = blockIdx.x;
    const float* r = S + row * (long long)LQ_N;
    const int t = threadIdx.x;
    float4 v = ((const float4*)r)[t];

    float m = fmaxf(fmaxf(v.x, v.y), fmaxf(v.z, v.w));
#pragma unroll
    for (int off = 32; off > 0; off >>= 1)
        m = fmaxf(m, __shfl_xor(m, off));

    __shared__ float red[4];
    const int lane = t & 63, wid = t >> 6;
    if (lane == 0) red[wid] = m;
    __syncthreads();
    m = fmaxf(fmaxf(red[0], red[1]), fmaxf(red[2], red[3]));
    __syncthreads();

    v.x = __expf(v.x - m); v.y = __expf(v.y - m);
    v.z = __expf(v.z - m); v.w = __expf(v.w - m);
    float s = v.x + v.y + v.z + v.w;
#pragma unroll
    for (int off = 32; off > 0; off >>= 1)
        s += __shfl_xor(s, off);
    if (lane == 0) red[wid] = s;
    __syncthreads();
    s = red[0] + red[1] + red[2] + red[3];

    const float inv = 1.0f / s;
    ushort4 o;
    o.x = f2bf(v.x * inv); o.y = f2bf(v.y * inv);
    o.z = f2bf(v.z * inv); o.w = f2bf(v.w * inv);
    ((ushort4*)(A + row * (long long)LQ_N))[t] = o;
}

// ---------------------------------------------------------------------------
// Fallback fp32 path (round-1, verified; needs only 128 MB ws)
// ---------------------------------------------------------------------------
#define BM 128
#define BN 128
#define BK 8
#define TM 8
#define TN 8

template<bool TRANSB, bool BIAS, bool RELU>
__launch_bounds__(256)
__global__ void gemm_k(const float* __restrict__ A, const float* __restrict__ Bmat,
                       const float* __restrict__ bias, float* __restrict__ C,
                       int M, int N, int K,
                       long long sA, long long sB, long long sC)
{
    __shared__ float As[BK][BM];
    __shared__ float Bs[BK][BN];
    const int tid = threadIdx.x;
    const int tx = tid & 15;
    const int ty = tid >> 4;
    const int bn = blockIdx.x * BN;
    const int bm = blockIdx.y * BM;
    const long long z = blockIdx.z;
    A += z * sA; Bmat += z * sB; C += z * sC;
    float acc[TM][TN];
#pragma unroll
    for (int i = 0; i < TM; i++)
#pragma unroll
        for (int j = 0; j < TN; j++) acc[i][j] = 0.f;
    const int arow = tid >> 1;
    const int acol = (tid & 1) * 4;
    const int bk_n = tid >> 5;
    const int bn_n = (tid & 31) * 4;
    for (int k0 = 0; k0 < K; k0 += BK) {
        float4 a4 = *(const float4*)&A[(long long)(bm + arow) * K + k0 + acol];
        As[acol + 0][arow] = a4.x; As[acol + 1][arow] = a4.y;
        As[acol + 2][arow] = a4.z; As[acol + 3][arow] = a4.w;
        if (TRANSB) {
            float4 b4 = *(const float4*)&Bmat[(long long)(bn + arow) * K + k0 + acol];
            Bs[acol + 0][arow] = b4.x; Bs[acol + 1][arow] = b4.y;
            Bs[acol + 2][arow] = b4.z; Bs[acol + 3][arow] = b4.w;
        } else {
            float4 b4 = *(const float4*)&Bmat[(long long)(k0 + bk_n) * N + bn + bn_n];
            *(float4*)&Bs[bk_n][bn_n] = b4;
        }
        __syncthreads();
#pragma unroll
        for (int k = 0; k < BK; k++) {
            float a[TM], b[TN];
            *(float4*)&a[0] = *(const float4*)&As[k][ty * TM];
            *(float4*)&a[4] = *(const float4*)&As[k][ty * TM + 4];
            *(float4*)&b[0] = *(const float4*)&Bs[k][tx * TN];
            *(float4*)&b[4] = *(const float4*)&Bs[k][tx * TN + 4];
#pragma unroll
            for (int i = 0; i < TM; i++)
#pragma unroll
                for (int j = 0; j < TN; j++)
                    acc[i][j] = fmaf(a[i], b[j], acc[i][j]);
        }
        __syncthreads();
    }
#pragma unroll
    for (int i = 0; i < TM; i++) {
        const int row = bm + ty * TM + i;
#pragma unroll
        for (int j = 0; j < TN; j += 4) {
            const int col = bn + tx * TN + j;
            float4 v;
            v.x = acc[i][j + 0]; v.y = acc[i][j + 1];
            v.z = acc[i][j + 2]; v.w = acc[i][j + 3];
            if (BIAS) {
                v.x += bias[col + 0]; v.y += bias[col + 1];
                v.z += bias[col + 2]; v.w += bias[col + 3];
            }
            if (RELU) {
                v.x = fmaxf(v.x, 0.f); v.y = fmaxf(v.y, 0.f);
                v.z = fmaxf(v.z, 0.f); v.w = fmaxf(v.w, 0.f);
            }
            *(float4*)&C[(long long)row * N + col] = v;
        }
    }
}

__global__ void softmax_k(float* __restrict__ S)
{
    const long long row = blockIdx.x;
    float* r = S + row * (long long)LQ_N;
    const int t = threadIdx.x;
    float4 v = ((float4*)r)[t];
    float m = fmaxf(fmaxf(v.x, v.y), fmaxf(v.z, v.w));
#pragma unroll
    for (int off = 32; off > 0; off >>= 1)
        m = fmaxf(m, __shfl_xor(m, off));
    __shared__ float red[4];
    const int lane = t & 63, wid = t >> 6;
    if (lane == 0) red[wid] = m;
    __syncthreads();
    m = fmaxf(fmaxf(red[0], red[1]), fmaxf(red[2], red[3]));
    __syncthreads();
    v.x = __expf(v.x - m); v.y = __expf(v.y - m);
    v.z = __expf(v.z - m); v.w = __expf(v.w - m);
    float s = v.x + v.y + v.z + v.w;
#pragma unroll
    for (int off = 32; off > 0; off >>= 1)
        s += __shfl_xor(s, off);
    if (lane == 0) red[wid] = s;
    __syncthreads();
    s = red[0] + red[1] + red[2] + red[3];
    const float inv = 1.0f / s;
    v.x *= inv; v.y *= inv; v.z *= inv; v.w *= inv;
    ((float4*)r)[t] = v;
}

extern "C" void kernel_launch(void* const* d_in, const int* in_sizes, int n_in,
                              void* d_out, int out_size, void* d_ws, size_t ws_size,
                              hipStream_t stream)
{
    const float* p    = (const float*)d_in[0];
    const float* q    = (const float*)d_in[1];
    const float* W    = (const float*)d_in[2];
    const float* bias = (const float*)d_in[3];
    float* out = (float*)d_out;

    const size_t MB32 = 33554432ull;                 // 16M bf16
    const size_t NEED = 7 * MB32 + 2 * 2097152ull;   // 228 MB + 4 MB

    if (ws_size >= NEED) {
        char* w = (char*)d_ws;
        u16* p_hi    = (u16*)(w + 0 * MB32);
        u16* p_lo    = (u16*)(w + 1 * MB32);
        u16* q_hi    = (u16*)(w + 2 * MB32);
        u16* q_lo    = (u16*)(w + 3 * MB32);
        u16* keys_hi = (u16*)(w + 4 * MB32);
        u16* keys_lo = (u16*)(w + 5 * MB32);
        u16* qT_hi   = (u16*)(w + 6 * MB32);
        u16* Wt_hi   = (u16*)(w + 7 * MB32);
        u16* Wt_lo   = (u16*)(w + 7 * MB32 + 2097152);
        float* scores = (float*)(w + 2 * MB32);  // reuses q_hi/q_lo after GEMM1
        u16* attn     = (u16*)(w + 0 * MB32);    // reuses p_hi after GEMM2

        const long long n4 = (long long)B_N * LQ_N * H_N / 4;
        split_cvt<<<dim3((unsigned)(n4 / 256)), 256, 0, stream>>>(p, p_hi, p_lo, n4);
        split_cvt<<<dim3((unsigned)(n4 / 256)), 256, 0, stream>>>(q, q_hi, q_lo, n4);
        transpose_cvt<true><<<dim3(32, 32, 1), dim3(32, 8), 0, stream>>>(
            W, Wt_hi, Wt_lo, H_N, H_N, 0, 0);
        transpose_cvt<false><<<dim3(32, 32, B_N), dim3(32, 8), 0, stream>>>(
            q, qT_hi, nullptr, LQ_N, H_N,
            (long long)LQ_N * H_N, (long long)LQ_N * H_N);

        // keys = q @ W + b : K-concat [q_hi|q_hi|q_lo] x [W_hi|W_lo|W_hi].
        // M=16384 (batch folded), N=1024. grid 64x4 = 256.
        gemm_pipe<3, 1><<<256, 512, 0, stream>>>(
            q_hi, q_hi, q_lo, Wt_hi, Wt_lo, Wt_hi, bias,
            nullptr, keys_hi, keys_lo,
            H_N, /*gn=*/4, /*gmn=*/256, 0, 0, 0);

        // scores[b] = p[b] @ keys[b]^T : [p_hi|p_hi|p_lo] x [k_hi|k_lo|k_hi].
        gemm_pipe<3, 0><<<256, 512, 0, stream>>>(
            p_hi, p_hi, p_lo, keys_hi, keys_lo, keys_hi, nullptr,
            scores, nullptr, nullptr,
            LQ_N, /*gn=*/4, /*gmn=*/16,
            (long long)LP_N * H_N, (long long)LQ_N * H_N, (long long)LP_N * LQ_N);

        softmax_bf16<<<B_N * LP_N, 256, 0, stream>>>(scores, attn);

        // out[b] = relu(attn[b] @ q[b]) : dense bf16, K=1024.
        gemm_pipe<1, 2><<<256, 512, 0, stream>>>(
            attn, attn, attn, qT_hi, qT_hi, qT_hi, nullptr,
            out, nullptr, nullptr,
            H_N, /*gn=*/4, /*gmn=*/16,
            (long long)LP_N * LQ_N, (long long)H_N * LQ_N, (long long)LP_N * H_N);
    } else {
        float* keys   = (float*)d_ws;
        float* scores = keys + (long long)B_N * LQ_N * H_N;

        gemm_k<false, true, false><<<dim3(H_N / BN, (B_N * LQ_N) / BM, 1), 256, 0, stream>>>(
            q, W, bias, keys, B_N * LQ_N, H_N, H_N, 0, 0, 0);
        gemm_k<true, false, false><<<dim3(LQ_N / BN, LP_N / BM, B_N), 256, 0, stream>>>(
            p, keys, nullptr, scores, LP_N, LQ_N, H_N,
            (long long)LP_N * H_N, (long long)LQ_N * H_N, (long long)LP_N * LQ_N);
        softmax_k<<<B_N * LP_N, 256, 0, stream>>>(scores);
        gemm_k<false, false, true><<<dim3(H_N / BN, LP_N / BM, B_N), 256, 0, stream>>>(
            scores, q, nullptr, out, LP_N, H_N, LQ_N,
            (long long)LP_N * LQ_N, (long long)LQ_N * H_N, (long long)LP_N * H_N);
    }
}